// Round 1
// baseline (230.476 us; speedup 1.0000x reference)
//
#include <hip/hip_runtime.h>
#include <hip/hip_bf16.h>

#define BATCH 32
#define LSEQ  512
#define NDIM  1024

typedef __attribute__((ext_vector_type(8))) short bf16x8;
typedef __attribute__((ext_vector_type(4))) float f32x4;

__device__ __forceinline__ unsigned short f2bf(float x) {
    __hip_bfloat16 h = __float2bfloat16(x);
    return __builtin_bit_cast(unsigned short, h);
}

// ---------------------------------------------------------------------------
// Kernel 1: fused X fp32 -> bf16 conversion + s1/s2 reduction (atomic partials)
// grid (16 l-splits, 32 batches) x 256 threads; thread t owns n = 4t..4t+3
// ---------------------------------------------------------------------------
__global__ __launch_bounds__(256) void prep_kernel(
    const float* __restrict__ X, const float* __restrict__ W,
    unsigned short* __restrict__ Xb, float* __restrict__ s1, float* __restrict__ s2)
{
    __shared__ float sw[2 * LSEQ];
    int tid = threadIdx.x;
    for (int i = tid; i < 2 * LSEQ; i += 256) sw[i] = W[i];
    __syncthreads();

    int b  = blockIdx.y;
    int l0 = blockIdx.x * 32;
    size_t base = ((size_t)b * LSEQ + l0) * NDIM + tid * 4;
    const float* xp = X + base;
    unsigned short* xbp = Xb + base;

    float a0=0,a1=0,a2=0,a3=0, c0=0,c1=0,c2=0,c3=0;
    for (int l = 0; l < 32; ++l) {
        float4 x = *(const float4*)(xp + (size_t)l * NDIM);
        float w1 = sw[l0 + l], w2 = sw[LSEQ + l0 + l];
        a0 = fmaf(x.x, w1, a0); a1 = fmaf(x.y, w1, a1);
        a2 = fmaf(x.z, w1, a2); a3 = fmaf(x.w, w1, a3);
        c0 = fmaf(x.x, w2, c0); c1 = fmaf(x.y, w2, c1);
        c2 = fmaf(x.z, w2, c2); c3 = fmaf(x.w, w2, c3);
        ushort4 u; u.x = f2bf(x.x); u.y = f2bf(x.y); u.z = f2bf(x.z); u.w = f2bf(x.w);
        *(ushort4*)(xbp + (size_t)l * NDIM) = u;
    }
    float* p1 = s1 + b * NDIM + tid * 4;
    atomicAdd(p1 + 0, a0); atomicAdd(p1 + 1, a1);
    atomicAdd(p1 + 2, a2); atomicAdd(p1 + 3, a3);
    float* p2 = s2 + b * NDIM + tid * 4;
    atomicAdd(p2 + 0, c0); atomicAdd(p2 + 1, c1);
    atomicAdd(p2 + 2, c2); atomicAdd(p2 + 3, c3);
}

// ---------------------------------------------------------------------------
// Kernel 2: per-(b,j) softmax stats over i: m[b,j]=max_i e, rd[b,j]=1/sum exp
// e[i] = (i==j) ? 0 : lrelu(s1[i]+s2[j]).  One wave per (b,j).
// ---------------------------------------------------------------------------
__global__ __launch_bounds__(256) void rowstats_kernel(
    const float* __restrict__ s1, const float* __restrict__ s2,
    float* __restrict__ m, float* __restrict__ rd)
{
    int wid = threadIdx.x >> 6, lane = threadIdx.x & 63;
    int r = blockIdx.x * 4 + wid;          // (b,j) flat
    int b = r >> 10, j = r & 1023;
    const float* s1b = s1 + b * NDIM;
    float s2j = s2[r];

    float e[16];
    float mx = -1e30f;
    #pragma unroll
    for (int t = 0; t < 16; ++t) {
        int i = lane + 64 * t;
        float v = s1b[i] + s2j;
        v = v > 0.f ? v : 0.01f * v;
        if (i == j) v = 0.f;               // diag of e zeroed BEFORE softmax
        e[t] = v;
        mx = fmaxf(mx, v);
    }
    #pragma unroll
    for (int off = 32; off; off >>= 1) mx = fmaxf(mx, __shfl_xor(mx, off));
    float sum = 0.f;
    #pragma unroll
    for (int t = 0; t < 16; ++t) sum += __expf(e[t] - mx);
    #pragma unroll
    for (int off = 32; off; off >>= 1) sum += __shfl_xor(sum, off);
    if (lane == 0) { m[r] = mx; rd[r] = 1.0f / sum; }
}

// ---------------------------------------------------------------------------
// Kernel 3: generate Bt[b][i][j] = alpha[b,i,j] in bf16, j contiguous
// (this is the GEMM B-operand in [n][k] layout: n=i, k=j).
// One wave per (b,i); lane owns 4 contiguous j per pass, 4 passes.
// ---------------------------------------------------------------------------
__global__ __launch_bounds__(256) void btgen_kernel(
    const float* __restrict__ s1, const float* __restrict__ s2,
    const float* __restrict__ m, const float* __restrict__ rd,
    unsigned short* __restrict__ Bt)
{
    int wid = threadIdx.x >> 6, lane = threadIdx.x & 63;
    int r = blockIdx.x * 4 + wid;          // (b,i) flat
    int b = r >> 10, i = r & 1023;
    float s1i = s1[r];
    const float* s2b = s2 + b * NDIM;
    const float* mb  = m  + b * NDIM;
    const float* rdb = rd + b * NDIM;
    unsigned short* outp = Bt + (size_t)r * NDIM;

    #pragma unroll
    for (int q = 0; q < 4; ++q) {
        int j0 = q * 256 + lane * 4;
        float4 s2v = *(const float4*)(s2b + j0);
        float4 mv  = *(const float4*)(mb  + j0);
        float4 rv  = *(const float4*)(rdb + j0);
        float ev[4] = { s1i + s2v.x, s1i + s2v.y, s1i + s2v.z, s1i + s2v.w };
        float mm[4] = { mv.x, mv.y, mv.z, mv.w };
        float rr[4] = { rv.x, rv.y, rv.z, rv.w };
        ushort4 u;
        unsigned short us[4];
        #pragma unroll
        for (int k = 0; k < 4; ++k) {
            float e = ev[k];
            e = e > 0.f ? e : 0.01f * e;
            if (j0 + k == i) e = 0.f;      // diag element (alpha there is nonzero!)
            us[k] = f2bf(__expf(e - mm[k]) * rr[k]);
        }
        u.x = us[0]; u.y = us[1]; u.z = us[2]; u.w = us[3];
        *(ushort4*)(outp + j0) = u;
    }
}

// ---------------------------------------------------------------------------
// Kernel 4: batched GEMM  out[b] = sigmoid( Xb[b] (512x1024) @ Bt[b]^T )
// m97 structure: 128x128 tile, BK=32, 4 waves (2x2), 16x16x32 bf16 MFMA,
// global_load_lds width-16 staging, sigmoid epilogue. K=1024 -> 32 iters.
// ---------------------------------------------------------------------------
__global__ __launch_bounds__(256) void gemm_kernel(
    const unsigned short* __restrict__ Xb, const unsigned short* __restrict__ Bt,
    float* __restrict__ out)
{
    __shared__ __align__(16) unsigned short Xs[128 * 32];
    __shared__ __align__(16) unsigned short Bs[128 * 32];

    int tid = threadIdx.x, wid = tid >> 6, lane = tid & 63;
    int wm = wid >> 1, wn = wid & 1;
    int b = blockIdx.z, l0 = blockIdx.y * 128, n0 = blockIdx.x * 128;

    const unsigned short* Xg = Xb + ((size_t)b * LSEQ + l0) * NDIM;
    const unsigned short* Bg = Bt + ((size_t)b * NDIM + n0) * NDIM;

    int rin = lane >> 2, ch = lane & 3;    // staging: 4 lanes per 64B row

    f32x4 acc[4][4] = {};

    for (int kb = 0; kb < 32; ++kb) {
        int k0 = kb * 32;
        __syncthreads();                   // protect LDS from prior-iter readers
        #pragma unroll
        for (int q = 0; q < 2; ++q) {
            int row = wid * 32 + q * 16 + rin;
            const unsigned short* gx = Xg + (size_t)row * NDIM + k0 + ch * 8;
            const unsigned short* gb = Bg + (size_t)row * NDIM + k0 + ch * 8;
            unsigned short* lx = &Xs[(wid * 32 + q * 16) * 32];  // wave-uniform base
            unsigned short* lb = &Bs[(wid * 32 + q * 16) * 32];
            __builtin_amdgcn_global_load_lds(
                (const __attribute__((address_space(1))) void*)gx,
                (__attribute__((address_space(3))) void*)lx, 16, 0, 0);
            __builtin_amdgcn_global_load_lds(
                (const __attribute__((address_space(1))) void*)gb,
                (__attribute__((address_space(3))) void*)lb, 16, 0, 0);
        }
        __syncthreads();                   // compiler inserts vmcnt(0) drain

        bf16x8 av[4], bv[4];
        int rsel = lane & 15, ksel = (lane >> 4) * 8;
        #pragma unroll
        for (int mi = 0; mi < 4; ++mi)
            av[mi] = *(const bf16x8*)&Xs[(wm * 64 + mi * 16 + rsel) * 32 + ksel];
        #pragma unroll
        for (int ni = 0; ni < 4; ++ni)
            bv[ni] = *(const bf16x8*)&Bs[(wn * 64 + ni * 16 + rsel) * 32 + ksel];
        #pragma unroll
        for (int mi = 0; mi < 4; ++mi)
            #pragma unroll
            for (int ni = 0; ni < 4; ++ni)
                acc[mi][ni] = __builtin_amdgcn_mfma_f32_16x16x32_bf16(
                    av[mi], bv[ni], acc[mi][ni], 0, 0, 0);
    }

    // epilogue: C/D layout col=lane&15, row=(lane>>4)*4+reg  [m89/m91 verified]
    float* outb = out + ((size_t)b * LSEQ + l0) * NDIM + n0;
    int rq = lane >> 4, cl = lane & 15;
    #pragma unroll
    for (int mi = 0; mi < 4; ++mi)
        #pragma unroll
        for (int ni = 0; ni < 4; ++ni) {
            int col = wn * 64 + ni * 16 + cl;
            #pragma unroll
            for (int r2 = 0; r2 < 4; ++r2) {
                int row = wm * 64 + mi * 16 + rq * 4 + r2;
                float v = acc[mi][ni][r2];
                outb[(size_t)row * NDIM + col] = 1.0f / (1.0f + __expf(-v));
            }
        }
}

// ---------------------------------------------------------------------------
extern "C" void kernel_launch(void* const* d_in, const int* in_sizes, int n_in,
                              void* d_out, int out_size, void* d_ws, size_t ws_size,
                              hipStream_t stream) {
    (void)in_sizes; (void)n_in; (void)out_size; (void)ws_size;
    const float* X = (const float*)d_in[0];
    const float* W = (const float*)d_in[1];
    float* out = (float*)d_out;

    // workspace layout: s1|s2|m|rd (32K floats each) | Xb bf16 32MB | Bt bf16 64MB
    float* s1 = (float*)d_ws;
    float* s2 = s1 + BATCH * NDIM;
    float* mrow = s2 + BATCH * NDIM;
    float* rd = mrow + BATCH * NDIM;
    unsigned short* Xb = (unsigned short*)(rd + BATCH * NDIM);
    unsigned short* Bt = Xb + (size_t)BATCH * LSEQ * NDIM;

    hipMemsetAsync(s1, 0, (size_t)2 * BATCH * NDIM * sizeof(float), stream);
    prep_kernel<<<dim3(16, BATCH), 256, 0, stream>>>(X, W, Xb, s1, s2);
    rowstats_kernel<<<(BATCH * NDIM) / 4, 256, 0, stream>>>(s1, s2, mrow, rd);
    btgen_kernel<<<(BATCH * NDIM) / 4, 256, 0, stream>>>(s1, s2, mrow, rd, Bt);
    gemm_kernel<<<dim3(NDIM / 128, LSEQ / 128, BATCH), 256, 0, stream>>>(Xb, Bt, out);
}

// Round 2
// 204.207 us; speedup vs baseline: 1.1286x; 1.1286x over previous
//
#include <hip/hip_runtime.h>
#include <hip/hip_bf16.h>

#define BATCH 32
#define LSEQ  512
#define NDIM  1024
#define NSPLIT 16

typedef __attribute__((ext_vector_type(8))) short bf16x8;
typedef __attribute__((ext_vector_type(4))) float f32x4;

__device__ __forceinline__ unsigned short f2bf(float x) {
    __hip_bfloat16 h = __float2bfloat16(x);
    return __builtin_bit_cast(unsigned short, h);
}

// ---------------------------------------------------------------------------
// Kernel 1: fused X fp32 -> bf16 conversion + s1/s2 partial sums (no atomics)
// grid (NSPLIT l-splits, 32 batches) x 256 threads; thread t owns n = 4t..4t+3
// Partials: P1/P2 [split][b][n]
// ---------------------------------------------------------------------------
__global__ __launch_bounds__(256) void prep_kernel(
    const float* __restrict__ X, const float* __restrict__ W,
    unsigned short* __restrict__ Xb, float* __restrict__ P1, float* __restrict__ P2)
{
    __shared__ float sw[2 * LSEQ];
    int tid = threadIdx.x;
    for (int i = tid; i < 2 * LSEQ; i += 256) sw[i] = W[i];
    __syncthreads();

    int b  = blockIdx.y;
    int sp = blockIdx.x;
    int l0 = sp * (LSEQ / NSPLIT);
    size_t base = ((size_t)b * LSEQ + l0) * NDIM + tid * 4;
    const float* xp = X + base;
    unsigned short* xbp = Xb + base;

    float a0=0,a1=0,a2=0,a3=0, c0=0,c1=0,c2=0,c3=0;
    for (int l = 0; l < LSEQ / NSPLIT; ++l) {
        float4 x = *(const float4*)(xp + (size_t)l * NDIM);
        float w1 = sw[l0 + l], w2 = sw[LSEQ + l0 + l];
        a0 = fmaf(x.x, w1, a0); a1 = fmaf(x.y, w1, a1);
        a2 = fmaf(x.z, w1, a2); a3 = fmaf(x.w, w1, a3);
        c0 = fmaf(x.x, w2, c0); c1 = fmaf(x.y, w2, c1);
        c2 = fmaf(x.z, w2, c2); c3 = fmaf(x.w, w2, c3);
        ushort4 u; u.x = f2bf(x.x); u.y = f2bf(x.y); u.z = f2bf(x.z); u.w = f2bf(x.w);
        *(ushort4*)(xbp + (size_t)l * NDIM) = u;
    }
    size_t po = ((size_t)sp * BATCH + b) * NDIM + tid * 4;
    *(float4*)(P1 + po) = make_float4(a0, a1, a2, a3);
    *(float4*)(P2 + po) = make_float4(c0, c1, c2, c3);
}

// ---------------------------------------------------------------------------
// Kernel 1b: reduce partials -> s1, s2.  32768 outputs each; 128 blocks x 256.
// ---------------------------------------------------------------------------
__global__ __launch_bounds__(256) void reduce_kernel(
    const float* __restrict__ P1, const float* __restrict__ P2,
    float* __restrict__ s1, float* __restrict__ s2)
{
    int o = blockIdx.x * 256 + threadIdx.x;   // (b,n) flat, 0..32767
    float a = 0.f, c = 0.f;
    #pragma unroll
    for (int sp = 0; sp < NSPLIT; ++sp) {
        a += P1[(size_t)sp * BATCH * NDIM + o];
        c += P2[(size_t)sp * BATCH * NDIM + o];
    }
    s1[o] = a; s2[o] = c;
}

// ---------------------------------------------------------------------------
// Kernel 2: per-(b,j) softmax stats over i: m[b,j]=max_i e, rd[b,j]=1/sum exp
// e[i] = (i==j) ? 0 : lrelu(s1[i]+s2[j]).  One wave per (b,j).
// ---------------------------------------------------------------------------
__global__ __launch_bounds__(256) void rowstats_kernel(
    const float* __restrict__ s1, const float* __restrict__ s2,
    float* __restrict__ m, float* __restrict__ rd)
{
    int wid = threadIdx.x >> 6, lane = threadIdx.x & 63;
    int r = blockIdx.x * 4 + wid;          // (b,j) flat
    int b = r >> 10, j = r & 1023;
    const float* s1b = s1 + b * NDIM;
    float s2j = s2[r];

    float e[16];
    float mx = -1e30f;
    #pragma unroll
    for (int t = 0; t < 16; ++t) {
        int i = lane + 64 * t;
        float v = s1b[i] + s2j;
        v = v > 0.f ? v : 0.01f * v;
        if (i == j) v = 0.f;               // diag of e zeroed BEFORE softmax
        e[t] = v;
        mx = fmaxf(mx, v);
    }
    #pragma unroll
    for (int off = 32; off; off >>= 1) mx = fmaxf(mx, __shfl_xor(mx, off));
    float sum = 0.f;
    #pragma unroll
    for (int t = 0; t < 16; ++t) sum += __expf(e[t] - mx);
    #pragma unroll
    for (int off = 32; off; off >>= 1) sum += __shfl_xor(sum, off);
    if (lane == 0) { m[r] = mx; rd[r] = 1.0f / sum; }
}

// ---------------------------------------------------------------------------
// Kernel 3: generate Bt[b][i][j] = alpha[b,i,j] in bf16, j contiguous
// (GEMM B-operand in [n][k] layout: n=i, k=j). One wave per (b,i).
// ---------------------------------------------------------------------------
__global__ __launch_bounds__(256) void btgen_kernel(
    const float* __restrict__ s1, const float* __restrict__ s2,
    const float* __restrict__ m, const float* __restrict__ rd,
    unsigned short* __restrict__ Bt)
{
    int wid = threadIdx.x >> 6, lane = threadIdx.x & 63;
    int r = blockIdx.x * 4 + wid;          // (b,i) flat
    int b = r >> 10, i = r & 1023;
    float s1i = s1[r];
    const float* s2b = s2 + b * NDIM;
    const float* mb  = m  + b * NDIM;
    const float* rdb = rd + b * NDIM;
    unsigned short* outp = Bt + (size_t)r * NDIM;

    #pragma unroll
    for (int q = 0; q < 4; ++q) {
        int j0 = q * 256 + lane * 4;
        float4 s2v = *(const float4*)(s2b + j0);
        float4 mv  = *(const float4*)(mb  + j0);
        float4 rv  = *(const float4*)(rdb + j0);
        float ev[4] = { s1i + s2v.x, s1i + s2v.y, s1i + s2v.z, s1i + s2v.w };
        float mm[4] = { mv.x, mv.y, mv.z, mv.w };
        float rr[4] = { rv.x, rv.y, rv.z, rv.w };
        ushort4 u;
        unsigned short us[4];
        #pragma unroll
        for (int k = 0; k < 4; ++k) {
            float e = ev[k];
            e = e > 0.f ? e : 0.01f * e;
            if (j0 + k == i) e = 0.f;      // diag of e is zeroed (alpha nonzero there)
            us[k] = f2bf(__expf(e - mm[k]) * rr[k]);
        }
        u.x = us[0]; u.y = us[1]; u.z = us[2]; u.w = us[3];
        *(ushort4*)(outp + j0) = u;
    }
}

// ---------------------------------------------------------------------------
// Kernel 4: batched GEMM  out[b] = sigmoid( Xb[b] (512x1024) @ Bt[b]^T )
// 128x128 tile, BK=32, 4 waves (2x2), 16x16x32 bf16 MFMA, global_load_lds
// width-16 staging, sigmoid epilogue.
// XCD swizzle: flat grid of 1024; xcd = flat&7 gets batches {xcd, xcd+8, ...}
// one batch at a time -> per-XCD L2 working set = Xb[b] 1MB + Bt[b] 2MB = 3MB.
// ---------------------------------------------------------------------------
__global__ __launch_bounds__(256) void gemm_kernel(
    const unsigned short* __restrict__ Xb, const unsigned short* __restrict__ Bt,
    float* __restrict__ out)
{
    __shared__ __align__(16) unsigned short Xs[128 * 32];
    __shared__ __align__(16) unsigned short Bs[128 * 32];

    int tid = threadIdx.x, wid = tid >> 6, lane = tid & 63;
    int wm = wid >> 1, wn = wid & 1;

    // XCD-aware decode (HW round-robins flat block id % 8 across XCDs)
    int flat = blockIdx.x;
    int xcd   = flat & 7;
    int idx   = flat >> 3;          // 0..127 within XCD
    int bg    = idx >> 5;           // 0..3: which batch this XCD is on
    int inner = idx & 31;           // 0..31: tile within batch
    int b  = bg * 8 + xcd;
    int n0 = (inner & 7) * 128;
    int l0 = (inner >> 3) * 128;

    const unsigned short* Xg = Xb + ((size_t)b * LSEQ + l0) * NDIM;
    const unsigned short* Bg = Bt + ((size_t)b * NDIM + n0) * NDIM;

    int rin = lane >> 2, ch = lane & 3;    // staging: 4 lanes per 64B row

    f32x4 acc[4][4] = {};

    for (int kb = 0; kb < 32; ++kb) {
        int k0 = kb * 32;
        __syncthreads();                   // protect LDS from prior-iter readers
        #pragma unroll
        for (int q = 0; q < 2; ++q) {
            int row = wid * 32 + q * 16 + rin;
            const unsigned short* gx = Xg + (size_t)row * NDIM + k0 + ch * 8;
            const unsigned short* gb = Bg + (size_t)row * NDIM + k0 + ch * 8;
            unsigned short* lx = &Xs[(wid * 32 + q * 16) * 32];  // wave-uniform base
            unsigned short* lb = &Bs[(wid * 32 + q * 16) * 32];
            __builtin_amdgcn_global_load_lds(
                (const __attribute__((address_space(1))) void*)gx,
                (__attribute__((address_space(3))) void*)lx, 16, 0, 0);
            __builtin_amdgcn_global_load_lds(
                (const __attribute__((address_space(1))) void*)gb,
                (__attribute__((address_space(3))) void*)lb, 16, 0, 0);
        }
        __syncthreads();

        bf16x8 av[4], bv[4];
        int rsel = lane & 15, ksel = (lane >> 4) * 8;
        #pragma unroll
        for (int mi = 0; mi < 4; ++mi)
            av[mi] = *(const bf16x8*)&Xs[(wm * 64 + mi * 16 + rsel) * 32 + ksel];
        #pragma unroll
        for (int ni = 0; ni < 4; ++ni)
            bv[ni] = *(const bf16x8*)&Bs[(wn * 64 + ni * 16 + rsel) * 32 + ksel];
        #pragma unroll
        for (int mi = 0; mi < 4; ++mi)
            #pragma unroll
            for (int ni = 0; ni < 4; ++ni)
                acc[mi][ni] = __builtin_amdgcn_mfma_f32_16x16x32_bf16(
                    av[mi], bv[ni], acc[mi][ni], 0, 0, 0);
    }

    // epilogue: C/D layout col=lane&15, row=(lane>>4)*4+reg  [m89/m91 verified]
    float* outb = out + ((size_t)b * LSEQ + l0) * NDIM + n0;
    int rq = lane >> 4, cl = lane & 15;
    #pragma unroll
    for (int mi = 0; mi < 4; ++mi)
        #pragma unroll
        for (int ni = 0; ni < 4; ++ni) {
            int col = wn * 64 + ni * 16 + cl;
            #pragma unroll
            for (int r2 = 0; r2 < 4; ++r2) {
                int row = wm * 64 + mi * 16 + rq * 4 + r2;
                float v = acc[mi][ni][r2];
                outb[(size_t)row * NDIM + col] = 1.0f / (1.0f + __expf(-v));
            }
        }
}

// ---------------------------------------------------------------------------
extern "C" void kernel_launch(void* const* d_in, const int* in_sizes, int n_in,
                              void* d_out, int out_size, void* d_ws, size_t ws_size,
                              hipStream_t stream) {
    (void)in_sizes; (void)n_in; (void)out_size; (void)ws_size;
    const float* X = (const float*)d_in[0];
    const float* W = (const float*)d_in[1];
    float* out = (float*)d_out;

    // workspace: s1|s2|m|rd (32K floats each) | P1|P2 (512K floats each)
    //            | Xb bf16 32MB | Bt bf16 64MB
    float* s1 = (float*)d_ws;
    float* s2 = s1 + BATCH * NDIM;
    float* mrow = s2 + BATCH * NDIM;
    float* rd = mrow + BATCH * NDIM;
    float* P1 = rd + BATCH * NDIM;
    float* P2 = P1 + (size_t)NSPLIT * BATCH * NDIM;
    unsigned short* Xb = (unsigned short*)(P2 + (size_t)NSPLIT * BATCH * NDIM);
    unsigned short* Bt = Xb + (size_t)BATCH * LSEQ * NDIM;

    prep_kernel<<<dim3(NSPLIT, BATCH), 256, 0, stream>>>(X, W, Xb, P1, P2);
    reduce_kernel<<<(BATCH * NDIM) / 256, 256, 0, stream>>>(P1, P2, s1, s2);
    rowstats_kernel<<<(BATCH * NDIM) / 4, 256, 0, stream>>>(s1, s2, mrow, rd);
    btgen_kernel<<<(BATCH * NDIM) / 4, 256, 0, stream>>>(s1, s2, mrow, rd, Bt);
    gemm_kernel<<<1024, 256, 0, stream>>>(Xb, Bt, out);
}